// Round 16
// baseline (522.809 us; speedup 1.0000x reference)
//
#include <hip/hip_runtime.h>
#include <hip/hip_bf16.h>

// LSAPPNP: h = relu(x@W1+b1); h2 = h@W2+b2; agg[r] += val*h2[c] over edges;
// out = log_softmax(0.1*h2 + agg, axis=1)
// N=100000, F_IN=500, HID=256, C=40, E~2.3M
//
// Round 22 (instrumented): csr_spmm dispatched TWICE (idempotent) so its
// true duration = dur_us - ~437; if >128us it shows in top-5 directly.
// Real changes kept: k_transpose deleted (csr_spmm reads lofs[c][b]
// strided, L2-resident); split at 1024 thr (16 waves/CU, was 8, for the
// latency-bound scatter). MLP frozen at R18 geometry (128.7us).

#define N_NODES 100000
#define F_IN    500
#define HID     256
#define C_OUT   40
#define ALPHA0  0.1f
#define H2STRIDE 64

#define RPB     64                            // rows per bucket
#define NBUCK   ((N_NODES + RPB - 1) / RPB)   // 1563
#define NBUCKP  1568                          // padded (x32, >= NBUCK+1)
#define NCH     256                           // edge chunks
#define BCAPL   1792                          // bucket cap (mean 1474, +8.3 sigma)

typedef short short8 __attribute__((ext_vector_type(8)));
typedef float f32x4  __attribute__((ext_vector_type(4)));

__device__ __forceinline__ short f2bf(float f) {
  union { float f; unsigned u; } x; x.f = f;
  unsigned r = x.u + 0x7fffu + ((x.u >> 16) & 1u);  // RNE
  return (short)(r >> 16);
}
__device__ __forceinline__ float bf2f(short s) {
  union { unsigned u; float f; } x; x.u = ((unsigned)(unsigned short)s) << 16;
  return x.f;
}
// packed f32x2 -> bf16x2 (RNE), single VOP3
__device__ __forceinline__ unsigned cvtpk(float lo, float hi) {
  unsigned r;
  asm("v_cvt_pk_bf16_f32 %0, %1, %2" : "=v"(r) : "v"(lo), "v"(hi));
  return r;
}
// LDS-only barrier: drain DS ops, then raw s_barrier (no vmcnt drain).
__device__ __forceinline__ void lbar() {
  asm volatile("s_waitcnt lgkmcnt(0)" ::: "memory");
  __builtin_amdgcn_s_barrier();
}
// async global->LDS, 16B per lane; LDS dest = wave-uniform base + lane*16
__device__ __forceinline__ void gll16(const float* g, const char* l) {
  __builtin_amdgcn_global_load_lds(
      (const __attribute__((address_space(1))) void*)g,
      (__attribute__((address_space(3))) void*)l, 16, 0, 0);
}

// ---- K0: pack W1 -> W1S [16 kc][256 n][32 k] bf16; W2 -> W2T [48 n][256 k]
__global__ __launch_bounds__(256) void k_pack_weights(
    const float* __restrict__ W1, const float* __restrict__ W2,
    short* __restrict__ W1S, short* __restrict__ W2T)
{
  int i = blockIdx.x * 256 + threadIdx.x;
  if (i < 16*256*32) {
    int kc  = i >> 13;
    int idx = i & 8191;
    int n   = idx >> 5;
    int kk  = idx & 31;
    int k   = kc*32 + kk;
    float v = (k < F_IN) ? W1[k*HID + n] : 0.f;
    W1S[i] = f2bf(v);
  } else {
    int j = i - 16*256*32;
    if (j < 48*256) {
      int n = j >> 8;
      int k = j & 255;
      float v = (n < C_OUT) ? W2[k*C_OUT + n] : 0.f;
      W2T[j] = f2bf(v);
    }
  }
}

// ---- K1: fused MLP, 64-row tile, 256 thr = 4 waves. [R18 exact — frozen]
__global__ __launch_bounds__(256, 4) void k_fused_mlp(
    const float* __restrict__ x, const float* __restrict__ b1v,
    const float* __restrict__ b2v,
    const short* __restrict__ W1S, const short* __restrict__ W2T,
    short* __restrict__ h2b,
    const int* __restrict__ erow, int* __restrict__ lofs, int E, int CH)
{
  __shared__ __align__(16) char smem[32768];
  short (*Hl)[256] = (short(*)[256])smem;   // post-loop overlay, 32KB

  const int tid  = threadIdx.x;
  const int w    = tid >> 6;      // 0..3 = col-wave
  const int lane = tid & 63;
  const int lr   = lane & 15;
  const int quad = lane >> 4;
  const int row0 = blockIdx.x * 64;

  // staging: wave w owns chunks 2w, 2w+1 (rows 16w..16w+15, 8 rows/chunk)
  const int s_rl0 = (w*2)*8 + (lane>>3);
  const int s_rl1 = (w*2+1)*8 + (lane>>3);
  const int ksw   = ((lane&7) ^ ((lane>>3)&7)) * 4;
  const float* gp0 = x + (size_t)min(row0 + s_rl0, N_NODES-1) * F_IN;
  const float* gp1 = x + (size_t)min(row0 + s_rl1, N_NODES-1) * F_IN;
  const char* l0 = smem + (w*2)*1024;       // + buf*8192
  const char* l1 = smem + (w*2+1)*1024;

  f32x4 acc[4][4] = {};

  #pragma unroll
  for (int p = 0; p < 2; ++p) {
    int kb = p*32 + ksw;
    const float* a0 = (kb + 4 <= F_IN) ? gp0 + kb : x;
    const float* a1 = (kb + 4 <= F_IN) ? gp1 + kb : x;
    gll16(a0, l0 + p*8192);
    gll16(a1, l1 + p*8192);
  }

  const short* bbase = W1S + (w*64 + lr)*32 + quad*8;
  const int m2 = lr & 7;

  #pragma unroll
  for (int kc = 0; kc < 16; ++kc) {
    short8 bf4[4];
    #pragma unroll
    for (int t = 0; t < 4; ++t)
      bf4[t] = *(const short8*)(bbase + kc*8192 + t*16*32);
    __builtin_amdgcn_sched_barrier(0);

    if (kc < 14) {
      int kb = (kc+2)*32 + ksw;
      const float* a0 = (kb + 4 <= F_IN) ? gp0 + kb : x;
      const float* a1 = (kb + 4 <= F_IN) ? gp1 + kb : x;
      gll16(a0, l0 + ((kc+2)&3)*8192);
      gll16(a1, l1 + ((kc+2)&3)*8192);
      __builtin_amdgcn_sched_barrier(0);
      asm volatile("s_waitcnt vmcnt(8)" ::: "memory");
    } else if (kc == 14) {
      asm volatile("s_waitcnt vmcnt(6)" ::: "memory");
    } else {
      asm volatile("s_waitcnt vmcnt(4)" ::: "memory");
    }
    __builtin_amdgcn_s_barrier();

    const char* Abase = smem + (kc & 3)*8192;
    short8 af[4];
    #pragma unroll
    for (int t = 0; t < 4; ++t) {
      int rl = t*16 + lr;     // wave spans all 64 rows
      f32x4 u0 = *(const f32x4*)(Abase + rl*128 + (((quad*2  ) ^ m2) << 4));
      f32x4 u1 = *(const f32x4*)(Abase + rl*128 + (((quad*2+1) ^ m2) << 4));
      union { unsigned u[4]; short8 s; } pk;
      pk.u[0] = cvtpk(u0[0], u0[1]);
      pk.u[1] = cvtpk(u0[2], u0[3]);
      pk.u[2] = cvtpk(u1[0], u1[1]);
      pk.u[3] = cvtpk(u1[2], u1[3]);
      af[t] = pk.s;
    }

    #pragma unroll
    for (int rt = 0; rt < 4; ++rt)
      #pragma unroll
      for (int ct = 0; ct < 4; ++ct)
        acc[rt][ct] = __builtin_amdgcn_mfma_f32_16x16x32_bf16(af[rt], bf4[ct], acc[rt][ct], 0, 0, 0);
  }
  lbar();

  // epilogue 1: relu(acc + b1) -> Hl[64][256] (XOR-swizzled col groups)
  #pragma unroll
  for (int ct = 0; ct < 4; ++ct) {
    int col = w*64 + ct*16 + lr;
    int cg = col >> 3, ci = col & 7;
    float bias = b1v[col];
    #pragma unroll
    for (int rt = 0; rt < 4; ++rt) {
      #pragma unroll
      for (int r = 0; r < 4; ++r) {
        int row = rt*16 + quad*4 + r;
        float v = fmaxf(acc[rt][ct][r] + bias, 0.f);
        Hl[row][((cg ^ (row & 31)) << 3) | ci] = f2bf(v);
      }
    }
  }
  lbar();

  // GEMM2: wave w handles rows w*16..+15, 48 padded cols, K=256
  f32x4 acc2[3] = {};
  const int arow = w*16 + lr;
  #pragma unroll
  for (int kc2 = 0; kc2 < 8; ++kc2) {
    int gg = kc2*4 + quad;
    short8 a2 = *(const short8*)&Hl[arow][(gg ^ (arow & 31)) << 3];
    #pragma unroll
    for (int nt = 0; nt < 3; ++nt) {
      short8 b2 = *(const short8*)(W2T + (nt*16 + lr)*256 + kc2*32 + quad*8);
      acc2[nt] = __builtin_amdgcn_mfma_f32_16x16x32_bf16(a2, b2, acc2[nt], 0, 0, 0);
    }
  }

  // epilogue 2: h2b = bf16(acc2 + b2), stride 64, cols >= C_OUT zeroed
  #pragma unroll
  for (int nt = 0; nt < 3; ++nt) {
    int col = nt*16 + lr;
    float bias = (col < C_OUT) ? b2v[col] : 0.f;
    #pragma unroll
    for (int r = 0; r < 4; ++r) {
      int row = row0 + w*16 + quad*4 + r;
      if (row < N_NODES) {
        float v = (col < C_OUT) ? (acc2[nt][r] + bias) : 0.f;
        h2b[(long)row * H2STRIDE + col] = f2bf(v);
      }
    }
  }
  {
    int col = 48 + lr;
    #pragma unroll
    for (int r = 0; r < 4; ++r) {
      int row = row0 + w*16 + quad*4 + r;
      if (row < N_NODES) h2b[(long)row * H2STRIDE + col] = 0;
    }
  }

  // ---- folded hist + per-chunk scan: block bid handles chunk bid ----
  if (blockIdx.x < NCH) {
    int cc = blockIdx.x;
    int* hcnt = (int*)smem;                    // 1568 ints
    int* ssum = (int*)(smem + NBUCKP * 4);     // 256 ints
    lbar();                                    // Hl reads drained
    for (int b = tid; b < NBUCKP; b += 256) hcnt[b] = 0;
    __syncthreads();
    int e0 = cc * CH, e1 = min(E, e0 + CH);    // e0 multiple of 4
    if (e0 < e1) {
      int g0 = e0 >> 2, g1 = e1 >> 2;
      const int4* rp = (const int4*)erow;
      for (int g = g0 + tid; g < g1; g += 256) {
        int4 r4 = rp[g];
        atomicAdd(&hcnt[r4.x >> 6], 1);
        atomicAdd(&hcnt[r4.y >> 6], 1);
        atomicAdd(&hcnt[r4.z >> 6], 1);
        atomicAdd(&hcnt[r4.w >> 6], 1);
      }
      for (int e = (g1 << 2) + tid; e < e1; e += 256)
        atomicAdd(&hcnt[erow[e] >> 6], 1);
    }
    __syncthreads();
    // block exclusive scan over 1568 counts (8 consecutive per thread)
    int base = tid * 8;
    int d[8];
    int s = 0;
    #pragma unroll
    for (int k = 0; k < 8; ++k) {
      d[k] = (base + k < NBUCKP) ? hcnt[base + k] : 0;
      s += d[k];
    }
    ssum[tid] = s;
    __syncthreads();
    for (int o = 1; o < 256; o <<= 1) {
      int u = (tid >= o) ? ssum[tid - o] : 0;
      __syncthreads();
      if (tid >= o) ssum[tid] += u;
      __syncthreads();
    }
    int run = ssum[tid] - s;
    #pragma unroll
    for (int k = 0; k < 8; ++k) {
      if (base + k < NBUCKP) lofs[(size_t)cc * NBUCKP + base + k] = run;
      run += d[k];
    }
  }
}

// ---- K2: split edges chunk-major, 1024 thr (16 waves/CU TLP). Block c
// writes ONLY into its own contiguous window sorted[c*CH .. +CH).
__global__ __launch_bounds__(1024) void k_split(
    const int* __restrict__ erow, const int* __restrict__ ecol,
    const float* __restrict__ eval, const int* __restrict__ lofs,
    int2* __restrict__ sorted, int E, int CH)
{
  __shared__ int cur[NBUCK];
  int tid = threadIdx.x, c = blockIdx.x;

  for (int b = tid; b < NBUCK; b += 1024)
    cur[b] = lofs[(size_t)c * NBUCKP + b];   // per-chunk exclusive prefix
  __syncthreads();

  size_t obase = (size_t)c * CH;
  int e0 = c * CH, e1 = min(E, e0 + CH);
  if (e0 >= e1) return;
  int g0 = e0 >> 2, g1 = e1 >> 2;
  const int4*   rp = (const int4*)erow;
  const int4*   cp = (const int4*)ecol;
  const float4* vp = (const float4*)eval;
  for (int g = g0 + tid; g < g1; g += 1024) {
    int4 r4 = rp[g];
    int4 c4 = cp[g];
    float4 v4 = vp[g];
    int p0 = atomicAdd(&cur[r4.x >> 6], 1);
    int p1 = atomicAdd(&cur[r4.y >> 6], 1);
    int p2 = atomicAdd(&cur[r4.z >> 6], 1);
    int p3 = atomicAdd(&cur[r4.w >> 6], 1);
    int2 cv;
    cv.x = c4.x | ((r4.x & 63) << 17); cv.y = __float_as_int(v4.x); sorted[obase + p0] = cv;
    cv.x = c4.y | ((r4.y & 63) << 17); cv.y = __float_as_int(v4.y); sorted[obase + p1] = cv;
    cv.x = c4.z | ((r4.z & 63) << 17); cv.y = __float_as_int(v4.z); sorted[obase + p2] = cv;
    cv.x = c4.w | ((r4.w & 63) << 17); cv.y = __float_as_int(v4.w); sorted[obase + p3] = cv;
  }
  for (int e = (g1 << 2) + tid; e < e1; e += 1024) {
    int r = erow[e];
    int pos = atomicAdd(&cur[r >> 6], 1);
    int2 cv;
    cv.x = ecol[e] | ((r & 63) << 17);
    cv.y = __float_as_int(eval[e]);
    sorted[obase + pos] = cv;
  }
}

// ---- K3: bucket assembly + CSR sort (LDS) + wave-per-row SpMM + softmax.
// Reads lofs[c][b] directly (strided, L2-resident) — transpose deleted.
__global__ __launch_bounds__(512) void k_csr_spmm(
    const int* __restrict__ lofs, const int2* __restrict__ sorted,
    const short* __restrict__ h2b, float* __restrict__ out, int CH)
{
  __shared__ int2 eraw[BCAPL];    // 14336 B
  __shared__ int2 eS[BCAPL];      // 14336 B
  __shared__ int sA[NCH];
  __shared__ int cntc[NCH];
  __shared__ int cpos[NCH];       // inclusive prefix of cntc
  __shared__ int h[RPB], roff[RPB], cur[RPB];
  int tid = threadIdx.x, b = blockIdx.x;
  int lane = tid & 63, w = tid >> 6;

  if (tid < NCH) {
    int a  = lofs[(size_t)tid * NBUCKP + b];
    int e2 = lofs[(size_t)tid * NBUCKP + b + 1];
    sA[tid]   = a;
    cntc[tid] = e2 - a;
  }
  if (tid < RPB) h[tid] = 0;
  __syncthreads();
  // wave-0 shfl scan over 256 chunk counts (4 consecutive per lane)
  if (w == 0) {
    int c0v = cntc[lane*4], c1v = cntc[lane*4+1];
    int c2v = cntc[lane*4+2], c3v = cntc[lane*4+3];
    int s = c0v + c1v + c2v + c3v;
    int v = s;
    #pragma unroll
    for (int o = 1; o < 64; o <<= 1) {
      int t = __shfl_up(v, o);
      if (lane >= o) v += t;
    }
    int base = v - s;
    cpos[lane*4]     = base + c0v;
    cpos[lane*4 + 1] = base + c0v + c1v;
    cpos[lane*4 + 2] = base + c0v + c1v + c2v;
    cpos[lane*4 + 3] = v;
  }
  __syncthreads();
  int cntT = min(cpos[NCH - 1], BCAPL);

  // segment copy (2 threads per chunk) with fused row-histogram
  {
    int c    = tid & (NCH - 1);
    int half = tid >> 8;
    int srcb = c * CH + sA[c];
    int dstb = cpos[c] - cntc[c];
    int n    = cntc[c];
    for (int k = half; k < n; k += 2) {
      int p = dstb + k;
      if (p < BCAPL) {
        int2 cv = sorted[srcb + k];
        eraw[p] = cv;
        atomicAdd(&h[((unsigned)cv.x) >> 17], 1);
      }
    }
  }
  __syncthreads();
  // wave-0 inclusive shfl scan over 64 row counts
  if (w == 0) {
    int v = h[lane];
    int hv = v;
    #pragma unroll
    for (int o = 1; o < 64; o <<= 1) {
      int t = __shfl_up(v, o);
      if (lane >= o) v += t;
    }
    roff[lane] = v;
    cur[lane]  = v - hv;    // exclusive start
  }
  __syncthreads();
  // scatter into row-sorted LDS order
  for (int i = tid; i < cntT; i += 512) {
    int2 cv = eraw[i];
    int p = atomicAdd(&cur[((unsigned)cv.x) >> 17], 1);
    if (p < BCAPL) eS[p] = cv;
  }
  __syncthreads();

  // SpMM: wave w handles rows w*8 .. +7, 8-deep gather pipeline
  for (int rr = 0; rr < 8; ++rr) {
    int r = w * 8 + rr;
    int row = b * RPB + r;
    if (row >= N_NODES) continue;
    float acc = ALPHA0 * bf2f(h2b[(size_t)row * H2STRIDE + lane]);  // 0 for lane>=40
    int e  = roff[r] - h[r];
    int ee = roff[r];
    for (; e + 7 < ee; e += 8) {
      int2 cc[8];
      float gg[8];
      #pragma unroll
      for (int j = 0; j < 8; ++j) cc[j] = eS[e + j];
      #pragma unroll
      for (int j = 0; j < 8; ++j)
        gg[j] = bf2f(h2b[(size_t)(cc[j].x & 0x1FFFF) * H2STRIDE + lane]);
      #pragma unroll
      for (int j = 0; j < 8; ++j) acc += __int_as_float(cc[j].y) * gg[j];
    }
    for (; e + 3 < ee; e += 4) {
      int2 c0 = eS[e], c1 = eS[e+1], c2 = eS[e+2], c3 = eS[e+3];
      float g0 = bf2f(h2b[(size_t)(c0.x & 0x1FFFF) * H2STRIDE + lane]);
      float g1 = bf2f(h2b[(size_t)(c1.x & 0x1FFFF) * H2STRIDE + lane]);
      float g2 = bf2f(h2b[(size_t)(c2.x & 0x1FFFF) * H2STRIDE + lane]);
      float g3 = bf2f(h2b[(size_t)(c3.x & 0x1FFFF) * H2STRIDE + lane]);
      acc += __int_as_float(c0.y) * g0;
      acc += __int_as_float(c1.y) * g1;
      acc += __int_as_float(c2.y) * g2;
      acc += __int_as_float(c3.y) * g3;
    }
    for (; e < ee; ++e) {
      int2 c0 = eS[e];
      acc += __int_as_float(c0.y) * bf2f(h2b[(size_t)(c0.x & 0x1FFFF) * H2STRIDE + lane]);
    }
    float m = (lane < C_OUT) ? acc : -INFINITY;
    #pragma unroll
    for (int o = 32; o > 0; o >>= 1) m = fmaxf(m, __shfl_xor(m, o));
    float ev = (lane < C_OUT) ? __expf(acc - m) : 0.f;
    float s = ev;
    #pragma unroll
    for (int o = 32; o > 0; o >>= 1) s += __shfl_xor(s, o);
    if (lane < C_OUT) out[(long)row * C_OUT + lane] = acc - m - __logf(s);
  }
}

extern "C" void kernel_launch(void* const* d_in, const int* in_sizes, int n_in,
                              void* d_out, int out_size, void* d_ws, size_t ws_size,
                              hipStream_t stream) {
  const float* x    = (const float*)d_in[0];
  const float* W1   = (const float*)d_in[1];
  const float* b1   = (const float*)d_in[2];
  const float* W2   = (const float*)d_in[3];
  const float* b2   = (const float*)d_in[4];
  const int*   erow = (const int*)d_in[5];
  const int*   ecol = (const int*)d_in[6];
  const float* eval = (const float*)d_in[7];
  const int E  = in_sizes[5];
  int CH = (E + NCH - 1) / NCH;
  CH = (CH + 3) & ~3;                 // multiple of 4 for int4 alignment

  // ws: h2b 12.8MB | W1S 256KB | W2T 24KB | lofs 1.6MB | sorted ~18.4MB
  char* p = (char*)d_ws;
  short* h2b    = (short*)p;  p += (size_t)N_NODES * H2STRIDE * 2;
  short* W1S    = (short*)p;  p += (size_t)16*256*32 * 2;
  short* W2T    = (short*)p;  p += (size_t)48*256 * 2;
  int*   lofs   = (int*)p;    p += (size_t)NCH * NBUCKP * 4;
  int2*  sorted = (int2*)p;
  float* out = (float*)d_out;

  k_pack_weights<<<(16*256*32 + 48*256 + 255)/256, 256, 0, stream>>>(W1, W2, W1S, W2T);
  k_fused_mlp<<<(N_NODES + 63)/64, 256, 0, stream>>>(x, b1, b2, W1S, W2T, h2b,
                                                     erow, lofs, E, CH);
  k_split<<<NCH, 1024, 0, stream>>>(erow, ecol, eval, lofs, sorted, E, CH);
  // INSTRUMENTATION: dispatched twice (idempotent). True csr_spmm cost =
  // dur_us - ~437. Revert to single dispatch next round.
  k_csr_spmm<<<NBUCK, 512, 0, stream>>>(lofs, sorted, h2b, out, CH);
  k_csr_spmm<<<NBUCK, 512, 0, stream>>>(lofs, sorted, h2b, out, CH);
}

// Round 17
// 447.958 us; speedup vs baseline: 1.1671x; 1.1671x over previous
//
#include <hip/hip_runtime.h>
#include <hip/hip_bf16.h>

// LSAPPNP: h = relu(x@W1+b1); h2 = h@W2+b2; agg[r] += val*h2[c] over edges;
// out = log_softmax(0.1*h2 + agg, axis=1)
// N=100000, F_IN=500, HID=256, C=40, E~2.3M
//
// Round 23: R22's double-dispatch measured csr_spmm ~= 74us, exposing a
// ~200us FIXED harness constant (sum of kernels ~251us vs 454 total;
// consistent across all prior rounds). Revert to single csr dispatch;
// keep transpose-deletion + split@1024. csr_spmm -> 1024 thr (16 waves,
// 2 blocks/CU = 32 waves/CU): 2x TLP for the dominant L3 gather phase,
// 4 thr/chunk segment copy, 4 rows/wave SpMM. MLP frozen (R18, 129us).

#define N_NODES 100000
#define F_IN    500
#define HID     256
#define C_OUT   40
#define ALPHA0  0.1f
#define H2STRIDE 64

#define RPB     64                            // rows per bucket
#define NBUCK   ((N_NODES + RPB - 1) / RPB)   // 1563
#define NBUCKP  1568                          // padded (x32, >= NBUCK+1)
#define NCH     256                           // edge chunks
#define BCAPL   1792                          // bucket cap (mean 1474, +8.3 sigma)

typedef short short8 __attribute__((ext_vector_type(8)));
typedef float f32x4  __attribute__((ext_vector_type(4)));

__device__ __forceinline__ short f2bf(float f) {
  union { float f; unsigned u; } x; x.f = f;
  unsigned r = x.u + 0x7fffu + ((x.u >> 16) & 1u);  // RNE
  return (short)(r >> 16);
}
__device__ __forceinline__ float bf2f(short s) {
  union { unsigned u; float f; } x; x.u = ((unsigned)(unsigned short)s) << 16;
  return x.f;
}
// packed f32x2 -> bf16x2 (RNE), single VOP3
__device__ __forceinline__ unsigned cvtpk(float lo, float hi) {
  unsigned r;
  asm("v_cvt_pk_bf16_f32 %0, %1, %2" : "=v"(r) : "v"(lo), "v"(hi));
  return r;
}
// LDS-only barrier: drain DS ops, then raw s_barrier (no vmcnt drain).
__device__ __forceinline__ void lbar() {
  asm volatile("s_waitcnt lgkmcnt(0)" ::: "memory");
  __builtin_amdgcn_s_barrier();
}
// async global->LDS, 16B per lane; LDS dest = wave-uniform base + lane*16
__device__ __forceinline__ void gll16(const float* g, const char* l) {
  __builtin_amdgcn_global_load_lds(
      (const __attribute__((address_space(1))) void*)g,
      (__attribute__((address_space(3))) void*)l, 16, 0, 0);
}

// ---- K0: pack W1 -> W1S [16 kc][256 n][32 k] bf16; W2 -> W2T [48 n][256 k]
__global__ __launch_bounds__(256) void k_pack_weights(
    const float* __restrict__ W1, const float* __restrict__ W2,
    short* __restrict__ W1S, short* __restrict__ W2T)
{
  int i = blockIdx.x * 256 + threadIdx.x;
  if (i < 16*256*32) {
    int kc  = i >> 13;
    int idx = i & 8191;
    int n   = idx >> 5;
    int kk  = idx & 31;
    int k   = kc*32 + kk;
    float v = (k < F_IN) ? W1[k*HID + n] : 0.f;
    W1S[i] = f2bf(v);
  } else {
    int j = i - 16*256*32;
    if (j < 48*256) {
      int n = j >> 8;
      int k = j & 255;
      float v = (n < C_OUT) ? W2[k*C_OUT + n] : 0.f;
      W2T[j] = f2bf(v);
    }
  }
}

// ---- K1: fused MLP, 64-row tile, 256 thr = 4 waves. [R18 exact — frozen]
__global__ __launch_bounds__(256, 4) void k_fused_mlp(
    const float* __restrict__ x, const float* __restrict__ b1v,
    const float* __restrict__ b2v,
    const short* __restrict__ W1S, const short* __restrict__ W2T,
    short* __restrict__ h2b,
    const int* __restrict__ erow, int* __restrict__ lofs, int E, int CH)
{
  __shared__ __align__(16) char smem[32768];
  short (*Hl)[256] = (short(*)[256])smem;   // post-loop overlay, 32KB

  const int tid  = threadIdx.x;
  const int w    = tid >> 6;      // 0..3 = col-wave
  const int lane = tid & 63;
  const int lr   = lane & 15;
  const int quad = lane >> 4;
  const int row0 = blockIdx.x * 64;

  // staging: wave w owns chunks 2w, 2w+1 (rows 16w..16w+15, 8 rows/chunk)
  const int s_rl0 = (w*2)*8 + (lane>>3);
  const int s_rl1 = (w*2+1)*8 + (lane>>3);
  const int ksw   = ((lane&7) ^ ((lane>>3)&7)) * 4;
  const float* gp0 = x + (size_t)min(row0 + s_rl0, N_NODES-1) * F_IN;
  const float* gp1 = x + (size_t)min(row0 + s_rl1, N_NODES-1) * F_IN;
  const char* l0 = smem + (w*2)*1024;       // + buf*8192
  const char* l1 = smem + (w*2+1)*1024;

  f32x4 acc[4][4] = {};

  #pragma unroll
  for (int p = 0; p < 2; ++p) {
    int kb = p*32 + ksw;
    const float* a0 = (kb + 4 <= F_IN) ? gp0 + kb : x;
    const float* a1 = (kb + 4 <= F_IN) ? gp1 + kb : x;
    gll16(a0, l0 + p*8192);
    gll16(a1, l1 + p*8192);
  }

  const short* bbase = W1S + (w*64 + lr)*32 + quad*8;
  const int m2 = lr & 7;

  #pragma unroll
  for (int kc = 0; kc < 16; ++kc) {
    short8 bf4[4];
    #pragma unroll
    for (int t = 0; t < 4; ++t)
      bf4[t] = *(const short8*)(bbase + kc*8192 + t*16*32);
    __builtin_amdgcn_sched_barrier(0);

    if (kc < 14) {
      int kb = (kc+2)*32 + ksw;
      const float* a0 = (kb + 4 <= F_IN) ? gp0 + kb : x;
      const float* a1 = (kb + 4 <= F_IN) ? gp1 + kb : x;
      gll16(a0, l0 + ((kc+2)&3)*8192);
      gll16(a1, l1 + ((kc+2)&3)*8192);
      __builtin_amdgcn_sched_barrier(0);
      asm volatile("s_waitcnt vmcnt(8)" ::: "memory");
    } else if (kc == 14) {
      asm volatile("s_waitcnt vmcnt(6)" ::: "memory");
    } else {
      asm volatile("s_waitcnt vmcnt(4)" ::: "memory");
    }
    __builtin_amdgcn_s_barrier();

    const char* Abase = smem + (kc & 3)*8192;
    short8 af[4];
    #pragma unroll
    for (int t = 0; t < 4; ++t) {
      int rl = t*16 + lr;     // wave spans all 64 rows
      f32x4 u0 = *(const f32x4*)(Abase + rl*128 + (((quad*2  ) ^ m2) << 4));
      f32x4 u1 = *(const f32x4*)(Abase + rl*128 + (((quad*2+1) ^ m2) << 4));
      union { unsigned u[4]; short8 s; } pk;
      pk.u[0] = cvtpk(u0[0], u0[1]);
      pk.u[1] = cvtpk(u0[2], u0[3]);
      pk.u[2] = cvtpk(u1[0], u1[1]);
      pk.u[3] = cvtpk(u1[2], u1[3]);
      af[t] = pk.s;
    }

    #pragma unroll
    for (int rt = 0; rt < 4; ++rt)
      #pragma unroll
      for (int ct = 0; ct < 4; ++ct)
        acc[rt][ct] = __builtin_amdgcn_mfma_f32_16x16x32_bf16(af[rt], bf4[ct], acc[rt][ct], 0, 0, 0);
  }
  lbar();

  // epilogue 1: relu(acc + b1) -> Hl[64][256] (XOR-swizzled col groups)
  #pragma unroll
  for (int ct = 0; ct < 4; ++ct) {
    int col = w*64 + ct*16 + lr;
    int cg = col >> 3, ci = col & 7;
    float bias = b1v[col];
    #pragma unroll
    for (int rt = 0; rt < 4; ++rt) {
      #pragma unroll
      for (int r = 0; r < 4; ++r) {
        int row = rt*16 + quad*4 + r;
        float v = fmaxf(acc[rt][ct][r] + bias, 0.f);
        Hl[row][((cg ^ (row & 31)) << 3) | ci] = f2bf(v);
      }
    }
  }
  lbar();

  // GEMM2: wave w handles rows w*16..+15, 48 padded cols, K=256
  f32x4 acc2[3] = {};
  const int arow = w*16 + lr;
  #pragma unroll
  for (int kc2 = 0; kc2 < 8; ++kc2) {
    int gg = kc2*4 + quad;
    short8 a2 = *(const short8*)&Hl[arow][(gg ^ (arow & 31)) << 3];
    #pragma unroll
    for (int nt = 0; nt < 3; ++nt) {
      short8 b2 = *(const short8*)(W2T + (nt*16 + lr)*256 + kc2*32 + quad*8);
      acc2[nt] = __builtin_amdgcn_mfma_f32_16x16x32_bf16(a2, b2, acc2[nt], 0, 0, 0);
    }
  }

  // epilogue 2: h2b = bf16(acc2 + b2), stride 64, cols >= C_OUT zeroed
  #pragma unroll
  for (int nt = 0; nt < 3; ++nt) {
    int col = nt*16 + lr;
    float bias = (col < C_OUT) ? b2v[col] : 0.f;
    #pragma unroll
    for (int r = 0; r < 4; ++r) {
      int row = row0 + w*16 + quad*4 + r;
      if (row < N_NODES) {
        float v = (col < C_OUT) ? (acc2[nt][r] + bias) : 0.f;
        h2b[(long)row * H2STRIDE + col] = f2bf(v);
      }
    }
  }
  {
    int col = 48 + lr;
    #pragma unroll
    for (int r = 0; r < 4; ++r) {
      int row = row0 + w*16 + quad*4 + r;
      if (row < N_NODES) h2b[(long)row * H2STRIDE + col] = 0;
    }
  }

  // ---- folded hist + per-chunk scan: block bid handles chunk bid ----
  if (blockIdx.x < NCH) {
    int cc = blockIdx.x;
    int* hcnt = (int*)smem;                    // 1568 ints
    int* ssum = (int*)(smem + NBUCKP * 4);     // 256 ints
    lbar();                                    // Hl reads drained
    for (int b = tid; b < NBUCKP; b += 256) hcnt[b] = 0;
    __syncthreads();
    int e0 = cc * CH, e1 = min(E, e0 + CH);    // e0 multiple of 4
    if (e0 < e1) {
      int g0 = e0 >> 2, g1 = e1 >> 2;
      const int4* rp = (const int4*)erow;
      for (int g = g0 + tid; g < g1; g += 256) {
        int4 r4 = rp[g];
        atomicAdd(&hcnt[r4.x >> 6], 1);
        atomicAdd(&hcnt[r4.y >> 6], 1);
        atomicAdd(&hcnt[r4.z >> 6], 1);
        atomicAdd(&hcnt[r4.w >> 6], 1);
      }
      for (int e = (g1 << 2) + tid; e < e1; e += 256)
        atomicAdd(&hcnt[erow[e] >> 6], 1);
    }
    __syncthreads();
    // block exclusive scan over 1568 counts (8 consecutive per thread)
    int base = tid * 8;
    int d[8];
    int s = 0;
    #pragma unroll
    for (int k = 0; k < 8; ++k) {
      d[k] = (base + k < NBUCKP) ? hcnt[base + k] : 0;
      s += d[k];
    }
    ssum[tid] = s;
    __syncthreads();
    for (int o = 1; o < 256; o <<= 1) {
      int u = (tid >= o) ? ssum[tid - o] : 0;
      __syncthreads();
      if (tid >= o) ssum[tid] += u;
      __syncthreads();
    }
    int run = ssum[tid] - s;
    #pragma unroll
    for (int k = 0; k < 8; ++k) {
      if (base + k < NBUCKP) lofs[(size_t)cc * NBUCKP + base + k] = run;
      run += d[k];
    }
  }
}

// ---- K2: split edges chunk-major, 1024 thr. Block c writes ONLY into its
// own contiguous window sorted[c*CH .. +CH).
__global__ __launch_bounds__(1024) void k_split(
    const int* __restrict__ erow, const int* __restrict__ ecol,
    const float* __restrict__ eval, const int* __restrict__ lofs,
    int2* __restrict__ sorted, int E, int CH)
{
  __shared__ int cur[NBUCK];
  int tid = threadIdx.x, c = blockIdx.x;

  for (int b = tid; b < NBUCK; b += 1024)
    cur[b] = lofs[(size_t)c * NBUCKP + b];   // per-chunk exclusive prefix
  __syncthreads();

  size_t obase = (size_t)c * CH;
  int e0 = c * CH, e1 = min(E, e0 + CH);
  if (e0 >= e1) return;
  int g0 = e0 >> 2, g1 = e1 >> 2;
  const int4*   rp = (const int4*)erow;
  const int4*   cp = (const int4*)ecol;
  const float4* vp = (const float4*)eval;
  for (int g = g0 + tid; g < g1; g += 1024) {
    int4 r4 = rp[g];
    int4 c4 = cp[g];
    float4 v4 = vp[g];
    int p0 = atomicAdd(&cur[r4.x >> 6], 1);
    int p1 = atomicAdd(&cur[r4.y >> 6], 1);
    int p2 = atomicAdd(&cur[r4.z >> 6], 1);
    int p3 = atomicAdd(&cur[r4.w >> 6], 1);
    int2 cv;
    cv.x = c4.x | ((r4.x & 63) << 17); cv.y = __float_as_int(v4.x); sorted[obase + p0] = cv;
    cv.x = c4.y | ((r4.y & 63) << 17); cv.y = __float_as_int(v4.y); sorted[obase + p1] = cv;
    cv.x = c4.z | ((r4.z & 63) << 17); cv.y = __float_as_int(v4.z); sorted[obase + p2] = cv;
    cv.x = c4.w | ((r4.w & 63) << 17); cv.y = __float_as_int(v4.w); sorted[obase + p3] = cv;
  }
  for (int e = (g1 << 2) + tid; e < e1; e += 1024) {
    int r = erow[e];
    int pos = atomicAdd(&cur[r >> 6], 1);
    int2 cv;
    cv.x = ecol[e] | ((r & 63) << 17);
    cv.y = __float_as_int(eval[e]);
    sorted[obase + pos] = cv;
  }
}

// ---- K3: bucket assembly + CSR sort (LDS) + SpMM + softmax. 1024 thr =
// 16 waves (2 blocks/CU, 32 waves/CU): 2x gather TLP, 4 thr/chunk copy,
// 4 rows/wave SpMM. Reads lofs[c][b] strided (L2-resident).
__global__ __launch_bounds__(1024) void k_csr_spmm(
    const int* __restrict__ lofs, const int2* __restrict__ sorted,
    const short* __restrict__ h2b, float* __restrict__ out, int CH)
{
  __shared__ int2 eraw[BCAPL];    // 14336 B
  __shared__ int2 eS[BCAPL];      // 14336 B
  __shared__ int sA[NCH];
  __shared__ int cntc[NCH];
  __shared__ int cpos[NCH];       // inclusive prefix of cntc
  __shared__ int h[RPB], roff[RPB], cur[RPB];
  int tid = threadIdx.x, b = blockIdx.x;
  int lane = tid & 63, w = tid >> 6;   // w 0..15

  if (tid < NCH) {
    int a  = lofs[(size_t)tid * NBUCKP + b];
    int e2 = lofs[(size_t)tid * NBUCKP + b + 1];
    sA[tid]   = a;
    cntc[tid] = e2 - a;
  }
  if (tid < RPB) h[tid] = 0;
  __syncthreads();
  // wave-0 shfl scan over 256 chunk counts (4 consecutive per lane)
  if (w == 0) {
    int c0v = cntc[lane*4], c1v = cntc[lane*4+1];
    int c2v = cntc[lane*4+2], c3v = cntc[lane*4+3];
    int s = c0v + c1v + c2v + c3v;
    int v = s;
    #pragma unroll
    for (int o = 1; o < 64; o <<= 1) {
      int t = __shfl_up(v, o);
      if (lane >= o) v += t;
    }
    int base = v - s;
    cpos[lane*4]     = base + c0v;
    cpos[lane*4 + 1] = base + c0v + c1v;
    cpos[lane*4 + 2] = base + c0v + c1v + c2v;
    cpos[lane*4 + 3] = v;
  }
  __syncthreads();
  int cntT = min(cpos[NCH - 1], BCAPL);

  // segment copy (4 threads per chunk) with fused row-histogram
  {
    int c    = tid & (NCH - 1);
    int part = tid >> 8;            // 0..3
    int srcb = c * CH + sA[c];
    int dstb = cpos[c] - cntc[c];
    int n    = cntc[c];
    for (int k = part; k < n; k += 4) {
      int p = dstb + k;
      if (p < BCAPL) {
        int2 cv = sorted[srcb + k];
        eraw[p] = cv;
        atomicAdd(&h[((unsigned)cv.x) >> 17], 1);
      }
    }
  }
  __syncthreads();
  // wave-0 inclusive shfl scan over 64 row counts
  if (w == 0) {
    int v = h[lane];
    int hv = v;
    #pragma unroll
    for (int o = 1; o < 64; o <<= 1) {
      int t = __shfl_up(v, o);
      if (lane >= o) v += t;
    }
    roff[lane] = v;
    cur[lane]  = v - hv;    // exclusive start
  }
  __syncthreads();
  // scatter into row-sorted LDS order
  for (int i = tid; i < cntT; i += 1024) {
    int2 cv = eraw[i];
    int p = atomicAdd(&cur[((unsigned)cv.x) >> 17], 1);
    if (p < BCAPL) eS[p] = cv;
  }
  __syncthreads();

  // SpMM: wave w handles rows w*4 .. +3, 8-deep gather pipeline
  for (int rr = 0; rr < 4; ++rr) {
    int r = w * 4 + rr;
    int row = b * RPB + r;
    if (row >= N_NODES) continue;
    float acc = ALPHA0 * bf2f(h2b[(size_t)row * H2STRIDE + lane]);  // 0 for lane>=40
    int e  = roff[r] - h[r];
    int ee = roff[r];
    for (; e + 7 < ee; e += 8) {
      int2 cc[8];
      float gg[8];
      #pragma unroll
      for (int j = 0; j < 8; ++j) cc[j] = eS[e + j];
      #pragma unroll
      for (int j = 0; j < 8; ++j)
        gg[j] = bf2f(h2b[(size_t)(cc[j].x & 0x1FFFF) * H2STRIDE + lane]);
      #pragma unroll
      for (int j = 0; j < 8; ++j) acc += __int_as_float(cc[j].y) * gg[j];
    }
    for (; e + 3 < ee; e += 4) {
      int2 c0 = eS[e], c1 = eS[e+1], c2 = eS[e+2], c3 = eS[e+3];
      float g0 = bf2f(h2b[(size_t)(c0.x & 0x1FFFF) * H2STRIDE + lane]);
      float g1 = bf2f(h2b[(size_t)(c1.x & 0x1FFFF) * H2STRIDE + lane]);
      float g2 = bf2f(h2b[(size_t)(c2.x & 0x1FFFF) * H2STRIDE + lane]);
      float g3 = bf2f(h2b[(size_t)(c3.x & 0x1FFFF) * H2STRIDE + lane]);
      acc += __int_as_float(c0.y) * g0;
      acc += __int_as_float(c1.y) * g1;
      acc += __int_as_float(c2.y) * g2;
      acc += __int_as_float(c3.y) * g3;
    }
    for (; e < ee; ++e) {
      int2 c0 = eS[e];
      acc += __int_as_float(c0.y) * bf2f(h2b[(size_t)(c0.x & 0x1FFFF) * H2STRIDE + lane]);
    }
    float m = (lane < C_OUT) ? acc : -INFINITY;
    #pragma unroll
    for (int o = 32; o > 0; o >>= 1) m = fmaxf(m, __shfl_xor(m, o));
    float ev = (lane < C_OUT) ? __expf(acc - m) : 0.f;
    float s = ev;
    #pragma unroll
    for (int o = 32; o > 0; o >>= 1) s += __shfl_xor(s, o);
    if (lane < C_OUT) out[(long)row * C_OUT + lane] = acc - m - __logf(s);
  }
}

extern "C" void kernel_launch(void* const* d_in, const int* in_sizes, int n_in,
                              void* d_out, int out_size, void* d_ws, size_t ws_size,
                              hipStream_t stream) {
  const float* x    = (const float*)d_in[0];
  const float* W1   = (const float*)d_in[1];
  const float* b1   = (const float*)d_in[2];
  const float* W2   = (const float*)d_in[3];
  const float* b2   = (const float*)d_in[4];
  const int*   erow = (const int*)d_in[5];
  const int*   ecol = (const int*)d_in[6];
  const float* eval = (const float*)d_in[7];
  const int E  = in_sizes[5];
  int CH = (E + NCH - 1) / NCH;
  CH = (CH + 3) & ~3;                 // multiple of 4 for int4 alignment

  // ws: h2b 12.8MB | W1S 256KB | W2T 24KB | lofs 1.6MB | sorted ~18.4MB
  char* p = (char*)d_ws;
  short* h2b    = (short*)p;  p += (size_t)N_NODES * H2STRIDE * 2;
  short* W1S    = (short*)p;  p += (size_t)16*256*32 * 2;
  short* W2T    = (short*)p;  p += (size_t)48*256 * 2;
  int*   lofs   = (int*)p;    p += (size_t)NCH * NBUCKP * 4;
  int2*  sorted = (int2*)p;
  float* out = (float*)d_out;

  k_pack_weights<<<(16*256*32 + 48*256 + 255)/256, 256, 0, stream>>>(W1, W2, W1S, W2T);
  k_fused_mlp<<<(N_NODES + 63)/64, 256, 0, stream>>>(x, b1, b2, W1S, W2T, h2b,
                                                     erow, lofs, E, CH);
  k_split<<<NCH, 1024, 0, stream>>>(erow, ecol, eval, lofs, sorted, E, CH);
  k_csr_spmm<<<NBUCK, 1024, 0, stream>>>(lofs, sorted, h2b, out, CH);
}